// Round 5
// baseline (713.112 us; speedup 1.0000x reference)
//
#include <hip/hip_runtime.h>

#define DIMC 1024
#define BATCH 8
#define SEQ 4096
#define BS (BATCH*SEQ)   // 32768
#define PCOL 2051

typedef unsigned short ushort_t;
typedef __attribute__((ext_vector_type(8))) short short8;
typedef __attribute__((ext_vector_type(4))) float f32x4;
typedef __attribute__((ext_vector_type(4))) unsigned short us4;

__device__ __forceinline__ float bf2f(ushort_t u) {
    union { unsigned u32; float f; } v; v.u32 = ((unsigned)u) << 16; return v.f;
}
__device__ __forceinline__ ushort_t f2bf(float f) {
    union { float f; unsigned u; } v; v.f = f;
    unsigned r = v.u + 0x7fffu + ((v.u >> 16) & 1u);
    return (ushort_t)(r >> 16);
}
__device__ __forceinline__ float gelu_exact(float x) {
    return 0.5f * x * (1.0f + erff(x * 0.7071067811865475f));
}
__device__ __forceinline__ void gld16(const ushort_t* g, ushort_t* l) {
    __builtin_amdgcn_global_load_lds(
        (const __attribute__((address_space(1))) unsigned int*)g,
        (__attribute__((address_space(3))) unsigned int*)l, 16, 0, 0);
}

// ---------------- elementwise f32 -> bf16 ----------------
__global__ void cvt_f32_bf16(const float* __restrict__ src, ushort_t* __restrict__ dst, int n) {
    int i = (blockIdx.x * 256 + threadIdx.x) * 4;
    if (i >= n) return;
    f32x4 v = *(const f32x4*)(src + i);
    us4 o;
    #pragma unroll
    for (int j = 0; j < 4; j++) o[j] = f2bf(v[j]);
    *(us4*)(dst + i) = o;
}

// ---------------- transpose + cvt: dst[n*K + k] = src[k*ld + n] ----------------
__global__ void transpose_cvt(const float* __restrict__ src, ushort_t* __restrict__ dst,
                              int ld, int K) {
    __shared__ float tile[32][33];
    int tx = threadIdx.x & 31, ty = threadIdx.x >> 5;   // 32 x 8
    int n0 = blockIdx.x * 32, k0 = blockIdx.y * 32;
    #pragma unroll
    for (int j = 0; j < 4; j++)
        tile[ty + j * 8][tx] = src[(size_t)(k0 + ty + j * 8) * ld + n0 + tx];
    __syncthreads();
    #pragma unroll
    for (int j = 0; j < 4; j++)
        dst[(size_t)(n0 + ty + j * 8) * K + k0 + tx] = f2bf(tile[tx][ty + j * 8]);
}

// ---------------- pack gate weight columns: wg[j*1024+d] = W_in[d*PCOL + 2048+j] ----------------
__global__ void pack_gatesw(const float* __restrict__ W_in, float* __restrict__ wg) {
    int d = blockIdx.x * 256 + threadIdx.x;
    if (d >= 1024) return;
    const float* p = W_in + (size_t)d * PCOL + 2048;
    wg[d] = p[0]; wg[1024 + d] = p[1]; wg[2048 + d] = p[2];
}

// ---------------- fused: ibf = bf16(input); gates[row] = input[row] . wg + b_in ----------------
__global__ void cvt_gates(const float* __restrict__ input, const float* __restrict__ wg,
                          const float* __restrict__ b_in, ushort_t* __restrict__ ibf,
                          float* __restrict__ gates) {
    int row = blockIdx.x, tid = threadIdx.x;
    int lane = tid & 63, wave = tid >> 6;
    size_t base = (size_t)row * 1024 + tid * 4;
    f32x4 v = *(const f32x4*)(input + base);
    us4 o;
    #pragma unroll
    for (int j = 0; j < 4; j++) o[j] = f2bf(v[j]);
    *(us4*)(ibf + base) = o;
    f32x4 w0v = *(const f32x4*)(wg + tid * 4);
    f32x4 w1v = *(const f32x4*)(wg + 1024 + tid * 4);
    f32x4 w2v = *(const f32x4*)(wg + 2048 + tid * 4);
    float a0 = 0, a1 = 0, a2 = 0;
    #pragma unroll
    for (int j = 0; j < 4; j++) { a0 += v[j] * w0v[j]; a1 += v[j] * w1v[j]; a2 += v[j] * w2v[j]; }
    #pragma unroll
    for (int off = 32; off; off >>= 1) {
        a0 += __shfl_down(a0, off, 64);
        a1 += __shfl_down(a1, off, 64);
        a2 += __shfl_down(a2, off, 64);
    }
    __shared__ float red[4][3];
    if (lane == 0) { red[wave][0] = a0; red[wave][1] = a1; red[wave][2] = a2; }
    __syncthreads();
    if (tid == 0) {
        gates[row * 4 + 0] = red[0][0] + red[1][0] + red[2][0] + red[3][0] + b_in[2048];
        gates[row * 4 + 1] = red[0][1] + red[1][1] + red[2][1] + red[3][1] + b_in[2049];
        gates[row * 4 + 2] = red[0][2] + red[1][2] + red[2][2] + red[3][2] + b_in[2050];
    }
}

// ============ 256x256 8-phase bf16 MFMA GEMM, persistent multi-tile ============
// C[M,N] = A[M,K] @ Bt[N,K]^T + bias, epilogue MODEs as before.
// Grid = 256 blocks (1/CU). bm-INNER traversal: each block owns tpb consecutive
// bm tiles at a FIXED bn. Same-row blocks (one per bn) stream the same A panel
// K-synchronized -> each A k-slab fetched once into L2, nbx-1 hits. B panel is
// the SAME panel every tile of a block -> re-stages hit L2/L3. Cross-tile
// pipelining: last K-iter's 3 spare stage slots prefetch the next tile's
// B(0), A(0), B(1); register-only epilogue hides that latency.
template<int MODE>
__global__ __launch_bounds__(512, 2)
void gemm256(const ushort_t* __restrict__ A, const ushort_t* __restrict__ Bt,
             const float* __restrict__ bias, void* __restrict__ C,
             const ushort_t* __restrict__ Q, const float* __restrict__ gates,
             const float* __restrict__ vb, int K, int ldc, int ldq, int nbxsh, int tpb) {
    __shared__ ushort_t lA[2][16384];
    __shared__ ushort_t lB[2][16384];
    const int tid = threadIdx.x, lane = tid & 63, wave = tid >> 6;
    const int lr = lane & 15, kq = lane >> 4;
    const int wrm = wave >> 2, wrn = wave & 3;

    // T1 + locality map: xcd = bid&7; within XCD, block l = bid>>3 (0..31):
    //   bn = l & (nbx-1), grp = l >> nbxsh; block's tiles: bm = bm0 + ti, ti<tpb
    //   bm0 = xcd*(rows per XCD) + grp*tpb
    const int bid = blockIdx.x;
    const int xcd = bid & 7, l = bid >> 3;
    const int bn = l & ((1 << nbxsh) - 1);
    const int grp = l >> nbxsh;
    const int bm0 = xcd * ((32 * tpb) >> nbxsh) + grp * tpb;

    // swizzled fragment read base (ushort index): chunk col XOR'd by row-bit-3
    const int xsw = kq ^ (((lr >> 3) & 1) << 1);
    const int fBase = lr * 32 + xsw * 8;

    // staging: per-thread inverse-swizzled global source offsets (ushort units),
    // wave-uniform LDS chunk bases. [h = half (128 rows)][j = load index]
    int srOff[2][2], ldsC[2][2];
    #pragma unroll
    for (int h = 0; h < 2; h++)
        #pragma unroll
        for (int j = 0; j < 2; j++) {
            int c = h * 1024 + j * 512 + tid;           // linear 16B-chunk id in tile
            int sub = c >> 6, rl = (c >> 2) & 15, cc = c & 3;
            int r  = ((sub >> 1) << 4) | rl;
            int k8 = ((sub & 1) << 2) | (cc ^ (((rl >> 3) & 1) << 1));
            srOff[h][j] = r * K + k8 * 8;
            ldsC[h][j]  = (h * 1024 + j * 512 + (wave << 6)) << 3;
        }

    f32x4 acc[8][4];
    short8 af[2][2], bfr[4][2];

#define STG(ARR, bb, G, kt, h) do { \
    gld16((G) + (size_t)(kt) * 64 + srOff[h][0], &ARR[bb][ldsC[h][0]]); \
    gld16((G) + (size_t)(kt) * 64 + srOff[h][1], &ARR[bb][ldsC[h][1]]); \
} while (0)

#define PHASE(bb, qq, STAGE_STMT, DOVM) do { \
    if ((qq) == 0) { \
        _Pragma("unroll") \
        for (int nt = 0; nt < 4; nt++) { \
            bfr[nt][0] = *(const short8*)&lB[bb][fBase + ((wrn * 4 + nt) * 2 + 0) * 512]; \
            bfr[nt][1] = *(const short8*)&lB[bb][fBase + ((wrn * 4 + nt) * 2 + 1) * 512]; \
        } \
    } \
    af[0][0] = *(const short8*)&lA[bb][fBase + ((wrm * 8 + (qq) * 2 + 0) * 2 + 0) * 512]; \
    af[0][1] = *(const short8*)&lA[bb][fBase + ((wrm * 8 + (qq) * 2 + 0) * 2 + 1) * 512]; \
    af[1][0] = *(const short8*)&lA[bb][fBase + ((wrm * 8 + (qq) * 2 + 1) * 2 + 0) * 512]; \
    af[1][1] = *(const short8*)&lA[bb][fBase + ((wrm * 8 + (qq) * 2 + 1) * 2 + 1) * 512]; \
    STAGE_STMT; \
    __builtin_amdgcn_s_barrier(); \
    asm volatile("s_waitcnt lgkmcnt(0)" ::: "memory"); \
    __builtin_amdgcn_s_setprio(1); \
    _Pragma("unroll") \
    for (int mi = 0; mi < 2; mi++) \
        _Pragma("unroll") \
        for (int nt = 0; nt < 4; nt++) { \
            acc[(qq) * 2 + mi][nt] = __builtin_amdgcn_mfma_f32_16x16x32_bf16( \
                af[mi][0], bfr[nt][0], acc[(qq) * 2 + mi][nt], 0, 0, 0); \
            acc[(qq) * 2 + mi][nt] = __builtin_amdgcn_mfma_f32_16x16x32_bf16( \
                af[mi][1], bfr[nt][1], acc[(qq) * 2 + mi][nt], 0, 0, 0); \
        } \
    __builtin_amdgcn_s_setprio(0); \
    if (DOVM) asm volatile("s_waitcnt vmcnt(4)" ::: "memory"); \
    __builtin_amdgcn_s_barrier(); \
} while (0)

    const int KT = K >> 6;   // k-tiles per output tile (16)
    const int IT = K >> 7;   // 8-phase iterations (8)

    int bm = bm0;
    const ushort_t* Ag = A + (size_t)bm * 256 * K;
    const ushort_t* Bg = Bt + (size_t)bn * 256 * K;   // constant across the block's tiles

    // block prologue (once): k-tile0 A+B -> buf0, k-tile1 B -> buf1
    STG(lA, 0, Ag, 0, 0); STG(lA, 0, Ag, 0, 1);
    STG(lB, 0, Bg, 0, 0); STG(lB, 0, Bg, 0, 1);
    STG(lB, 1, Bg, 1, 0); STG(lB, 1, Bg, 1, 1);
    asm volatile("s_waitcnt vmcnt(4)" ::: "memory");
    __builtin_amdgcn_s_barrier();

    for (int ti = 0; ti < tpb; ti++) {
        // next tile: bm+1 (clamped to self on the last tile -> dead restage)
        const int bmn = (ti < tpb - 1) ? bm + 1 : bm;
        const ushort_t* Agn = A + (size_t)bmn * 256 * K;

        #pragma unroll
        for (int i = 0; i < 8; i++)
            #pragma unroll
            for (int jj = 0; jj < 4; jj++)
                #pragma unroll
                for (int r = 0; r < 4; r++) acc[i][jj][r] = 0.f;

        // steady iterations: stage this tile's k-tiles t1..t3
        for (int it = 0; it < IT - 1; it++) {
            const int t1 = 2 * it + 1, t2 = 2 * it + 2, t3 = 2 * it + 3;
            PHASE(0, 0, STG(lA, 1, Ag, t1, 0), 0);
            PHASE(0, 1, STG(lA, 1, Ag, t1, 1), 0);
            PHASE(0, 2, STG(lB, 0, Bg, t2, 0), 0);
            PHASE(0, 3, STG(lB, 0, Bg, t2, 1), 1);
            PHASE(1, 0, STG(lA, 0, Ag, t2, 0), 0);
            PHASE(1, 1, STG(lA, 0, Ag, t2, 1), 0);
            PHASE(1, 2, STG(lB, 1, Bg, t3, 0), 0);
            PHASE(1, 3, STG(lB, 1, Bg, t3, 1), 1);
        }
        // last iteration: spare stage slots prefetch NEXT tile's prologue state
        // (B is the same panel -> these re-stages hit L2; A advances to bm+1)
        PHASE(0, 0, STG(lA, 1, Ag, KT - 1, 0), 0);
        PHASE(0, 1, STG(lA, 1, Ag, KT - 1, 1), 0);
        PHASE(0, 2, STG(lB, 0, Bg, 0, 0), 0);
        PHASE(0, 3, STG(lB, 0, Bg, 0, 1), 1);
        PHASE(1, 0, STG(lA, 0, Agn, 0, 0), 0);
        PHASE(1, 1, STG(lA, 0, Agn, 0, 1), 0);
        PHASE(1, 2, STG(lB, 1, Bg, 1, 0), 0);
        PHASE(1, 3, STG(lB, 1, Bg, 1, 1), 1);

        // register-only epilogue: overlaps the in-flight next-tile prologue.
        const int bbatch = (bm * 256) >> 12;   // batch index (uniform, SEQ=4096)
        #pragma unroll
        for (int mt = 0; mt < 8; mt++) {
            #pragma unroll
            for (int r = 0; r < 4; r++) {
                int row = bm * 256 + wrm * 128 + mt * 16 + kq * 4 + r;
                size_t rowc = (size_t)row * ldc;
                float g2;
                if (MODE == 1) g2 = gates[row * 4 + 2];
                #pragma unroll
                for (int nt = 0; nt < 4; nt++) {
                    int col = bn * 256 + wrn * 64 + nt * 16 + lr;
                    float v = acc[mt][nt][r] + bias[col];
                    if (MODE == 1) {
                        v += g2 * vb[bbatch * 1024 + col];
                        v *= bf2f(Q[(size_t)row * ldq + col]);
                    }
                    if (MODE == 2) ((float*)C)[rowc + col] = v;
                    else           ((ushort_t*)C)[rowc + col] = f2bf(v);
                }
            }
        }

        bm = bmn; Ag = Agn;
    }
#undef PHASE
#undef STG
    // Drain ALL in-flight ops (incl. dead-restage global_load_lds) before exit:
    // stray LDS writes landing after s_endpgm can corrupt a successor block.
    asm volatile("s_waitcnt vmcnt(0) lgkmcnt(0)" ::: "memory");
}

// ---------------- fused dwconv14 -> gelu -> dwconv18 -> gelu -> P = c0*g0 + c1*g1 ----------------
__global__ __launch_bounds__(256)
void dwconv_fused(const ushort_t* __restrict__ proj,   // ld=2048, ctx at col offset 1024
                  const float* __restrict__ w0, const float* __restrict__ b0,
                  const float* __restrict__ w1, const float* __restrict__ b1,
                  const float* __restrict__ gates,
                  ushort_t* __restrict__ P, float* __restrict__ G) {
    __shared__ float xc[94 * 64];
    __shared__ float x0[81 * 64];
    __shared__ float gl[2][64];
    __shared__ float rs[256];
    const int tid = threadIdx.x;
    const int s0 = blockIdx.x * 64, d0 = blockIdx.y * 64, b = blockIdx.z;
    for (int c = tid; c < 94 * 8; c += 256) {
        int r = c >> 3, dd = (c & 7) * 8;
        int s = s0 - 14 + r;
        float f[8];
        if (s >= 0 && s < SEQ) {
            short8 u = *(const short8*)&proj[(size_t)(b * SEQ + s) * 2048 + 1024 + d0 + dd];
            #pragma unroll
            for (int j = 0; j < 8; j++) f[j] = bf2f((ushort_t)u[j]);
        } else {
            #pragma unroll
            for (int j = 0; j < 8; j++) f[j] = 0.f;
        }
        f32x4 v0 = {f[0], f[1], f[2], f[3]}, v1 = {f[4], f[5], f[6], f[7]};
        *(f32x4*)&xc[r * 64 + dd] = v0;
        *(f32x4*)&xc[r * 64 + dd + 4] = v1;
    }
    if (tid < 64) gl[0][tid] = gates[(size_t)(b * SEQ + s0 + tid) * 4 + 0];
    else if (tid < 128) gl[1][tid - 64] = gates[(size_t)(b * SEQ + s0 + tid - 64) * 4 + 1];
    const int d = tid & 63, sc = tid >> 6;
    float wr0[14], wr1[18];
    #pragma unroll
    for (int t = 0; t < 14; t++) wr0[t] = w0[(size_t)(d0 + d) * 14 + t];
    float bb0 = b0[d0 + d];
    #pragma unroll
    for (int t = 0; t < 18; t++) wr1[t] = w1[(size_t)(d0 + d) * 18 + t];
    float bb1 = b1[d0 + d];
    __syncthreads();
    {
        float xw[34];
        int r0 = sc * 20;
        #pragma unroll
        for (int r = 0; r < 34; r++) xw[r] = xc[(r0 + r) * 64 + d];
        #pragma unroll
        for (int i = 0; i < 21; i++) {
            int rr = r0 + i;
            int s = s0 - 8 + rr;
            float acc = bb0;
            #pragma unroll
            for (int t = 0; t < 14; t++) acc += wr0[t] * xw[i + t];
            x0[rr * 64 + d] = (s >= 0 && s < SEQ) ? gelu_exact(acc) : 0.f;
        }
    }
    __syncthreads();
    float xw1[33];
    #pragma unroll
    for (int r = 0; r < 33; r++) xw1[r] = x0[(sc * 16 + r) * 64 + d];
    float psum = 0.f;
    #pragma unroll
    for (int i = 0; i < 16; i++) {
        float acc = bb1;
        #pragma unroll
        for (int t = 0; t < 18; t++) acc += wr1[t] * xw1[i + t];
        float c1 = gelu_exact(acc);
        psum += c1;
        float c0v = xw1[i + 8];
        int sl = sc * 16 + i;
        float pv = c0v * gl[0][sl] + c1 * gl[1][sl];
        P[(size_t)(b * SEQ + s0 + sl) * 1024 + d0 + d] = f2bf(pv);
    }
    rs[tid] = psum;
    __syncthreads();
    if (sc == 0)
        atomicAdd(&G[b * 1024 + d0 + d], rs[d] + rs[64 + d] + rs[128 + d] + rs[192 + d]);
}

// ---------------- v[b,o] = sum_c gelu(G[b,c]/SEQ) * Wctx[o,c] ----------------
__global__ __launch_bounds__(256)
void gemv_v(const float* __restrict__ G, const ushort_t* __restrict__ wctxB,
            float* __restrict__ v) {
    __shared__ float gg[1024];
    const int tid = threadIdx.x, b = blockIdx.y;
    for (int i = tid; i < 1024; i += 256)
        gg[i] = gelu_exact(G[b * 1024 + i] * (1.0f / (float)SEQ));
    __syncthreads();
    const int w = tid >> 6, lane = tid & 63;
    const int o = blockIdx.x * 4 + w;
    const ushort_t* wr = wctxB + (size_t)o * 1024;
    float acc = 0.f;
    #pragma unroll
    for (int j = 0; j < 16; j++)
        acc += gg[j * 64 + lane] * bf2f(wr[j * 64 + lane]);
    #pragma unroll
    for (int off = 32; off; off >>= 1) acc += __shfl_down(acc, off, 64);
    if (lane == 0) v[b * 1024 + o] = acc;
}

extern "C" void kernel_launch(void* const* d_in, const int* in_sizes, int n_in,
                              void* d_out, int out_size, void* d_ws, size_t ws_size,
                              hipStream_t stream) {
    const float* input = (const float*)d_in[0];
    const float* W_in  = (const float*)d_in[1];
    const float* b_in  = (const float*)d_in[2];
    const float* w0    = (const float*)d_in[3];
    const float* b0    = (const float*)d_in[4];
    const float* w1    = (const float*)d_in[5];
    const float* b1    = (const float*)d_in[6];
    const float* W_ctx = (const float*)d_in[7];
    const float* b_ctx = (const float*)d_in[8];
    const float* W_out = (const float*)d_in[9];
    const float* b_out = (const float*)d_in[10];

    char* ws = (char*)d_ws;
    size_t o = 0;
    ushort_t* ibf   = (ushort_t*)(ws + o); o += (size_t)BS * 1024 * 2;   // input bf16, reused as P
    ushort_t* proj  = (ushort_t*)(ws + o); o += (size_t)BS * 2048 * 2;   // [query | ctx] bf16
    ushort_t* Y     = (ushort_t*)(ws + o); o += (size_t)BS * 1024 * 2;
    float*    gates = (float*)   (ws + o); o += (size_t)BS * 4 * 4;
    float*    G     = (float*)   (ws + o); o += (size_t)BATCH * 1024 * 4;
    float*    v     = (float*)   (ws + o); o += (size_t)BATCH * 1024 * 4;
    float*    wg    = (float*)   (ws + o); o += (size_t)3 * 1024 * 4;
    ushort_t* winT  = (ushort_t*)(ws + o); o += (size_t)2048 * 1024 * 2;
    ushort_t* wctxB = (ushort_t*)(ws + o); o += (size_t)1024 * 1024 * 2;
    ushort_t* woutT = (ushort_t*)(ws + o); o += (size_t)1024 * 1024 * 2;
    ushort_t* P = ibf;   // safe: ibf last read by gemm0; dwconv_fused writes P after

    hipMemsetAsync(G, 0, BATCH * 1024 * sizeof(float), stream);
    // weight prep
    pack_gatesw<<<4, 256, 0, stream>>>(W_in, wg);
    transpose_cvt<<<dim3(2048 / 32, 1024 / 32), 256, 0, stream>>>(W_in, winT, PCOL, 1024);
    cvt_f32_bf16<<<1024 * 1024 / 4 / 256, 256, 0, stream>>>(W_ctx, wctxB, 1024 * 1024);
    transpose_cvt<<<dim3(1024 / 32, 1024 / 32), 256, 0, stream>>>(W_out, woutT, 1024, 1024);
    // input cvt + gates GEMV (fp32)
    cvt_gates<<<BS, 256, 0, stream>>>(input, wg, b_in, ibf, gates);
    // proj[:, 0:2048] = input @ W_in[:, 0:2048] + b_in   (1024 tiles: nbx=8, tpb=4)
    gemm256<0><<<dim3(256), 512, 0, stream>>>(ibf, winT, b_in, proj,
        nullptr, nullptr, nullptr, 1024, 2048, 0, 3, 4);
    // fused conv chain -> P (= c0*g0 + c1*g1), G (= sum_s c1)
    dwconv_fused<<<dim3(SEQ / 64, 16, BATCH), 256, 0, stream>>>(proj, w0, b0, w1, b1, gates, P, G);
    // v[b,:] = gelu(G/SEQ) @ Wctx^T
    gemv_v<<<dim3(256, BATCH), 256, 0, stream>>>(G, wctxB, v);
    // Y = query * (P @ Wctx^T + b_ctx + g2 (x) v)   (512 tiles: nbx=4, tpb=2)
    gemm256<1><<<dim3(256), 512, 0, stream>>>(P, wctxB, b_ctx, Y,
        proj, gates, v, 1024, 1024, 2048, 2, 2);
    // out = Y @ W_out + b_out  (fp32)  (512 tiles: nbx=4, tpb=2)
    gemm256<2><<<dim3(256), 512, 0, stream>>>(Y, woutT, b_out, d_out,
        nullptr, nullptr, nullptr, 1024, 1024, 0, 2, 2);
}

// Round 6
// 664.290 us; speedup vs baseline: 1.0735x; 1.0735x over previous
//
#include <hip/hip_runtime.h>

#define DIMC 1024
#define BATCH 8
#define SEQ 4096
#define BS (BATCH*SEQ)   // 32768
#define PCOL 2051

typedef unsigned short ushort_t;
typedef __attribute__((ext_vector_type(8))) short short8;
typedef __attribute__((ext_vector_type(4))) float f32x4;
typedef __attribute__((ext_vector_type(4))) unsigned short us4;

__device__ __forceinline__ float bf2f(ushort_t u) {
    union { unsigned u32; float f; } v; v.u32 = ((unsigned)u) << 16; return v.f;
}
__device__ __forceinline__ ushort_t f2bf(float f) {
    union { float f; unsigned u; } v; v.f = f;
    unsigned r = v.u + 0x7fffu + ((v.u >> 16) & 1u);
    return (ushort_t)(r >> 16);
}
__device__ __forceinline__ float gelu_exact(float x) {
    return 0.5f * x * (1.0f + erff(x * 0.7071067811865475f));
}
__device__ __forceinline__ void gld16(const ushort_t* g, ushort_t* l) {
    __builtin_amdgcn_global_load_lds(
        (const __attribute__((address_space(1))) unsigned int*)g,
        (__attribute__((address_space(3))) unsigned int*)l, 16, 0, 0);
}

// ---------------- elementwise f32 -> bf16 ----------------
__global__ void cvt_f32_bf16(const float* __restrict__ src, ushort_t* __restrict__ dst, int n) {
    int i = (blockIdx.x * 256 + threadIdx.x) * 4;
    if (i >= n) return;
    f32x4 v = *(const f32x4*)(src + i);
    us4 o;
    #pragma unroll
    for (int j = 0; j < 4; j++) o[j] = f2bf(v[j]);
    *(us4*)(dst + i) = o;
}

// ---------------- transpose + cvt: dst[n*K + k] = src[k*ld + n] ----------------
__global__ void transpose_cvt(const float* __restrict__ src, ushort_t* __restrict__ dst,
                              int ld, int K) {
    __shared__ float tile[32][33];
    int tx = threadIdx.x & 31, ty = threadIdx.x >> 5;   // 32 x 8
    int n0 = blockIdx.x * 32, k0 = blockIdx.y * 32;
    #pragma unroll
    for (int j = 0; j < 4; j++)
        tile[ty + j * 8][tx] = src[(size_t)(k0 + ty + j * 8) * ld + n0 + tx];
    __syncthreads();
    #pragma unroll
    for (int j = 0; j < 4; j++)
        dst[(size_t)(n0 + ty + j * 8) * K + k0 + tx] = f2bf(tile[tx][ty + j * 8]);
}

// ---------------- pack gate weight columns: wg[j*1024+d] = W_in[d*PCOL + 2048+j] ----------------
__global__ void pack_gatesw(const float* __restrict__ W_in, float* __restrict__ wg) {
    int d = blockIdx.x * 256 + threadIdx.x;
    if (d >= 1024) return;
    const float* p = W_in + (size_t)d * PCOL + 2048;
    wg[d] = p[0]; wg[1024 + d] = p[1]; wg[2048 + d] = p[2];
}

// ---------------- fused: ibf = bf16(input); gates[row] = input[row] . wg + b_in ----------------
__global__ void cvt_gates(const float* __restrict__ input, const float* __restrict__ wg,
                          const float* __restrict__ b_in, ushort_t* __restrict__ ibf,
                          float* __restrict__ gates) {
    int row = blockIdx.x, tid = threadIdx.x;
    int lane = tid & 63, wave = tid >> 6;
    size_t base = (size_t)row * 1024 + tid * 4;
    f32x4 v = *(const f32x4*)(input + base);
    us4 o;
    #pragma unroll
    for (int j = 0; j < 4; j++) o[j] = f2bf(v[j]);
    *(us4*)(ibf + base) = o;
    f32x4 w0v = *(const f32x4*)(wg + tid * 4);
    f32x4 w1v = *(const f32x4*)(wg + 1024 + tid * 4);
    f32x4 w2v = *(const f32x4*)(wg + 2048 + tid * 4);
    float a0 = 0, a1 = 0, a2 = 0;
    #pragma unroll
    for (int j = 0; j < 4; j++) { a0 += v[j] * w0v[j]; a1 += v[j] * w1v[j]; a2 += v[j] * w2v[j]; }
    #pragma unroll
    for (int off = 32; off; off >>= 1) {
        a0 += __shfl_down(a0, off, 64);
        a1 += __shfl_down(a1, off, 64);
        a2 += __shfl_down(a2, off, 64);
    }
    __shared__ float red[4][3];
    if (lane == 0) { red[wave][0] = a0; red[wave][1] = a1; red[wave][2] = a2; }
    __syncthreads();
    if (tid == 0) {
        gates[row * 4 + 0] = red[0][0] + red[1][0] + red[2][0] + red[3][0] + b_in[2048];
        gates[row * 4 + 1] = red[0][1] + red[1][1] + red[2][1] + red[3][1] + b_in[2049];
        gates[row * 4 + 2] = red[0][2] + red[1][2] + red[2][2] + red[3][2] + b_in[2050];
    }
}

// ============ 256x256 8-phase bf16 MFMA GEMM, persistent multi-tile ============
// bn-INNER traversal (R4, best measured): per-block A panel constant (L2-hot),
// B streams cold. Stage-slot asymmetry is matched to that: cold B is staged at
// P2/P3 and P6/P7 and waited at P8 / next-P4 (~5.5-6 phase lead, covers ~900cy
// HBM latency); hot A keeps the short 2.5-phase lead (covers ~300cy L2).
// vmcnt ledger (2 units per STG): each P4/P8 sees 12 in flight, waits to 4;
// invariants: lA[1],lB[1] landed before P5; lA[0],lB[0] before next P1.
template<int MODE>
__global__ __launch_bounds__(512, 2)
void gemm256(const ushort_t* __restrict__ A, const ushort_t* __restrict__ Bt,
             const float* __restrict__ bias, void* __restrict__ C,
             const ushort_t* __restrict__ Q, const float* __restrict__ gates,
             const float* __restrict__ vb, int K, int ldc, int ldq, int nbx, int tpb) {
    __shared__ ushort_t lA[2][16384];
    __shared__ ushort_t lB[2][16384];
    const int tid = threadIdx.x, lane = tid & 63, wave = tid >> 6;
    const int lr = lane & 15, kq = lane >> 4;
    const int wrm = wave >> 2, wrn = wave & 3;

    // T1: xcd = bid&7 owns a contiguous chunk of the tile space (j-linear,
    // bn-inner since tpb <= nbx and alignment keeps a block inside one bm row)
    const int bid = blockIdx.x;
    const int chunk = (gridDim.x >> 3) * tpb;
    const int tile0 = (bid & 7) * chunk + (bid >> 3) * tpb;

    // swizzled fragment read base (ushort index): chunk col XOR'd by row-bit-3
    const int xsw = kq ^ (((lr >> 3) & 1) << 1);
    const int fBase = lr * 32 + xsw * 8;

    // staging: per-thread inverse-swizzled global source offsets (ushort units),
    // wave-uniform LDS chunk bases. [h = half (128 rows)][j = load index]
    int srOff[2][2], ldsC[2][2];
    #pragma unroll
    for (int h = 0; h < 2; h++)
        #pragma unroll
        for (int j = 0; j < 2; j++) {
            int c = h * 1024 + j * 512 + tid;           // linear 16B-chunk id in tile
            int sub = c >> 6, rl = (c >> 2) & 15, cc = c & 3;
            int r  = ((sub >> 1) << 4) | rl;
            int k8 = ((sub & 1) << 2) | (cc ^ (((rl >> 3) & 1) << 1));
            srOff[h][j] = r * K + k8 * 8;
            ldsC[h][j]  = (h * 1024 + j * 512 + (wave << 6)) << 3;
        }

    f32x4 acc[8][4];
    short8 af[2][2], bfr[4][2];

#define STG(ARR, bb, G, kt, h) do { \
    gld16((G) + (size_t)(kt) * 64 + srOff[h][0], &ARR[bb][ldsC[h][0]]); \
    gld16((G) + (size_t)(kt) * 64 + srOff[h][1], &ARR[bb][ldsC[h][1]]); \
} while (0)

#define PHASE(bb, qq, STAGE_STMT, DOVM) do { \
    if ((qq) == 0) { \
        _Pragma("unroll") \
        for (int nt = 0; nt < 4; nt++) { \
            bfr[nt][0] = *(const short8*)&lB[bb][fBase + ((wrn * 4 + nt) * 2 + 0) * 512]; \
            bfr[nt][1] = *(const short8*)&lB[bb][fBase + ((wrn * 4 + nt) * 2 + 1) * 512]; \
        } \
    } \
    af[0][0] = *(const short8*)&lA[bb][fBase + ((wrm * 8 + (qq) * 2 + 0) * 2 + 0) * 512]; \
    af[0][1] = *(const short8*)&lA[bb][fBase + ((wrm * 8 + (qq) * 2 + 0) * 2 + 1) * 512]; \
    af[1][0] = *(const short8*)&lA[bb][fBase + ((wrm * 8 + (qq) * 2 + 1) * 2 + 0) * 512]; \
    af[1][1] = *(const short8*)&lA[bb][fBase + ((wrm * 8 + (qq) * 2 + 1) * 2 + 1) * 512]; \
    STAGE_STMT; \
    __builtin_amdgcn_s_barrier(); \
    asm volatile("s_waitcnt lgkmcnt(0)" ::: "memory"); \
    __builtin_amdgcn_s_setprio(1); \
    _Pragma("unroll") \
    for (int mi = 0; mi < 2; mi++) \
        _Pragma("unroll") \
        for (int nt = 0; nt < 4; nt++) { \
            acc[(qq) * 2 + mi][nt] = __builtin_amdgcn_mfma_f32_16x16x32_bf16( \
                af[mi][0], bfr[nt][0], acc[(qq) * 2 + mi][nt], 0, 0, 0); \
            acc[(qq) * 2 + mi][nt] = __builtin_amdgcn_mfma_f32_16x16x32_bf16( \
                af[mi][1], bfr[nt][1], acc[(qq) * 2 + mi][nt], 0, 0, 0); \
        } \
    __builtin_amdgcn_s_setprio(0); \
    if (DOVM) asm volatile("s_waitcnt vmcnt(4)" ::: "memory"); \
    __builtin_amdgcn_s_barrier(); \
} while (0)

    const int KT = K >> 6;   // k-tiles per output tile (16)
    const int IT = K >> 7;   // 8-phase iterations (8)

    int j = tile0;
    int bn = j % nbx, bm = j / nbx;
    const ushort_t* Ag = A + (size_t)bm * 256 * K;
    const ushort_t* Bg = Bt + (size_t)bn * 256 * K;

    // block prologue (once): tile j k-tile0 A+B -> buf0, k-tile1 B -> buf1
    STG(lA, 0, Ag, 0, 0); STG(lA, 0, Ag, 0, 1);
    STG(lB, 0, Bg, 0, 0); STG(lB, 0, Bg, 0, 1);
    STG(lB, 1, Bg, 1, 0); STG(lB, 1, Bg, 1, 1);
    asm volatile("s_waitcnt vmcnt(4)" ::: "memory");   // tile0 landed; B(1) in flight
    __builtin_amdgcn_s_barrier();

    for (int ti = 0; ti < tpb; ti++) {
        // next tile (clamped to self on the block's last tile -> dead restage)
        const int jn = (ti < tpb - 1) ? j + 1 : j;
        const int bnn = jn % nbx, bmn = jn / nbx;
        const ushort_t* Agn = A + (size_t)bmn * 256 * K;
        const ushort_t* Bgn = Bt + (size_t)bnn * 256 * K;

        #pragma unroll
        for (int i = 0; i < 8; i++)
            #pragma unroll
            for (int jj = 0; jj < 4; jj++)
                #pragma unroll
                for (int r = 0; r < 4; r++) acc[i][jj][r] = 0.f;

        // steady iterations. Stage slots (B one phase earlier than R4):
        //  P1: A(t+1)h0   P2: A(t+1)h1 + B(t+2)h0   P3: B(t+2)h1   P4: vmcnt(4)
        //  P5: A(t+2)h0   P6: A(t+2)h1 + B(t+3)h0   P7: B(t+3)h1   P8: vmcnt(4)
        for (int it = 0; it < IT - 1; it++) {
            const int t1 = 2 * it + 1, t2 = 2 * it + 2, t3 = 2 * it + 3;
            PHASE(0, 0, STG(lA, 1, Ag, t1, 0), 0);
            PHASE(0, 1, STG(lA, 1, Ag, t1, 1); STG(lB, 0, Bg, t2, 0), 0);
            PHASE(0, 2, STG(lB, 0, Bg, t2, 1), 0);
            PHASE(0, 3, (void)0, 1);
            PHASE(1, 0, STG(lA, 0, Ag, t2, 0), 0);
            PHASE(1, 1, STG(lA, 0, Ag, t2, 1); STG(lB, 1, Bg, t3, 0), 0);
            PHASE(1, 2, STG(lB, 1, Bg, t3, 1), 0);
            PHASE(1, 3, (void)0, 1);
        }
        // boundary iteration: spare slots prefetch NEXT tile's prologue state
        // (bn-inner: Agn == Ag panel (hot); Bgn is the cold one, on long lead)
        PHASE(0, 0, STG(lA, 1, Ag, KT - 1, 0), 0);
        PHASE(0, 1, STG(lA, 1, Ag, KT - 1, 1); STG(lB, 0, Bgn, 0, 0), 0);
        PHASE(0, 2, STG(lB, 0, Bgn, 0, 1), 0);
        PHASE(0, 3, (void)0, 1);
        PHASE(1, 0, STG(lA, 0, Agn, 0, 0), 0);
        PHASE(1, 1, STG(lA, 0, Agn, 0, 1); STG(lB, 1, Bgn, 1, 0), 0);
        PHASE(1, 2, STG(lB, 1, Bgn, 1, 1), 0);
        PHASE(1, 3, (void)0, 1);

        // register-only epilogue: overlaps the in-flight next-tile prologue.
        const int bbatch = (bm * 256) >> 12;   // batch index (uniform, SEQ=4096)
        float biasv[4], vbv[4];
        #pragma unroll
        for (int nt = 0; nt < 4; nt++) {
            int col = bn * 256 + wrn * 64 + nt * 16 + lr;
            biasv[nt] = bias[col];
            if (MODE == 1) vbv[nt] = vb[bbatch * 1024 + col];
        }
        #pragma unroll
        for (int mt = 0; mt < 8; mt++) {
            #pragma unroll
            for (int r = 0; r < 4; r++) {
                int row = bm * 256 + wrm * 128 + mt * 16 + kq * 4 + r;
                size_t rowc = (size_t)row * ldc;
                float g2;
                if (MODE == 1) g2 = gates[row * 4 + 2];
                #pragma unroll
                for (int nt = 0; nt < 4; nt++) {
                    int col = bn * 256 + wrn * 64 + nt * 16 + lr;
                    float v = acc[mt][nt][r] + biasv[nt];
                    if (MODE == 1) {
                        v += g2 * vbv[nt];
                        v *= bf2f(Q[(size_t)row * ldq + col]);
                    }
                    if (MODE == 2) ((float*)C)[rowc + col] = v;
                    else           ((ushort_t*)C)[rowc + col] = f2bf(v);
                }
            }
        }

        j = jn; bm = bmn; bn = bnn; Ag = Agn; Bg = Bgn;
    }
#undef PHASE
#undef STG
    // Drain ALL in-flight ops (incl. dead-restage global_load_lds) before exit:
    // stray LDS writes landing after s_endpgm can corrupt a successor block.
    asm volatile("s_waitcnt vmcnt(0) lgkmcnt(0)" ::: "memory");
}

// ---------------- fused dwconv14 -> gelu -> dwconv18 -> gelu -> P = c0*g0 + c1*g1 ----------------
__global__ __launch_bounds__(256)
void dwconv_fused(const ushort_t* __restrict__ proj,   // ld=2048, ctx at col offset 1024
                  const float* __restrict__ w0, const float* __restrict__ b0,
                  const float* __restrict__ w1, const float* __restrict__ b1,
                  const float* __restrict__ gates,
                  ushort_t* __restrict__ P, float* __restrict__ G) {
    __shared__ float xc[94 * 64];
    __shared__ float x0[81 * 64];
    __shared__ float gl[2][64];
    __shared__ float rs[256];
    const int tid = threadIdx.x;
    const int s0 = blockIdx.x * 64, d0 = blockIdx.y * 64, b = blockIdx.z;
    for (int c = tid; c < 94 * 8; c += 256) {
        int r = c >> 3, dd = (c & 7) * 8;
        int s = s0 - 14 + r;
        float f[8];
        if (s >= 0 && s < SEQ) {
            short8 u = *(const short8*)&proj[(size_t)(b * SEQ + s) * 2048 + 1024 + d0 + dd];
            #pragma unroll
            for (int j = 0; j < 8; j++) f[j] = bf2f((ushort_t)u[j]);
        } else {
            #pragma unroll
            for (int j = 0; j < 8; j++) f[j] = 0.f;
        }
        f32x4 v0 = {f[0], f[1], f[2], f[3]}, v1 = {f[4], f[5], f[6], f[7]};
        *(f32x4*)&xc[r * 64 + dd] = v0;
        *(f32x4*)&xc[r * 64 + dd + 4] = v1;
    }
    if (tid < 64) gl[0][tid] = gates[(size_t)(b * SEQ + s0 + tid) * 4 + 0];
    else if (tid < 128) gl[1][tid - 64] = gates[(size_t)(b * SEQ + s0 + tid - 64) * 4 + 1];
    const int d = tid & 63, sc = tid >> 6;
    float wr0[14], wr1[18];
    #pragma unroll
    for (int t = 0; t < 14; t++) wr0[t] = w0[(size_t)(d0 + d) * 14 + t];
    float bb0 = b0[d0 + d];
    #pragma unroll
    for (int t = 0; t < 18; t++) wr1[t] = w1[(size_t)(d0 + d) * 18 + t];
    float bb1 = b1[d0 + d];
    __syncthreads();
    {
        float xw[34];
        int r0 = sc * 20;
        #pragma unroll
        for (int r = 0; r < 34; r++) xw[r] = xc[(r0 + r) * 64 + d];
        #pragma unroll
        for (int i = 0; i < 21; i++) {
            int rr = r0 + i;
            int s = s0 - 8 + rr;
            float acc = bb0;
            #pragma unroll
            for (int t = 0; t < 14; t++) acc += wr0[t] * xw[i + t];
            x0[rr * 64 + d] = (s >= 0 && s < SEQ) ? gelu_exact(acc) : 0.f;
        }
    }
    __syncthreads();
    float xw1[33];
    #pragma unroll
    for (int r = 0; r < 33; r++) xw1[r] = x0[(sc * 16 + r) * 64 + d];
    float psum = 0.f;
    #pragma unroll
    for (int i = 0; i < 16; i++) {
        float acc = bb1;
        #pragma unroll
        for (int t = 0; t < 18; t++) acc += wr1[t] * xw1[i + t];
        float c1 = gelu_exact(acc);
        psum += c1;
        float c0v = xw1[i + 8];
        int sl = sc * 16 + i;
        float pv = c0v * gl[0][sl] + c1 * gl[1][sl];
        P[(size_t)(b * SEQ + s0 + sl) * 1024 + d0 + d] = f2bf(pv);
    }
    rs[tid] = psum;
    __syncthreads();
    if (sc == 0)
        atomicAdd(&G[b * 1024 + d0 + d], rs[d] + rs[64 + d] + rs[128 + d] + rs[192 + d]);
}

// ---------------- v[b,o] = sum_c gelu(G[b,c]/SEQ) * Wctx[o,c] ----------------
__global__ __launch_bounds__(256)
void gemv_v(const float* __restrict__ G, const ushort_t* __restrict__ wctxB,
            float* __restrict__ v) {
    __shared__ float gg[1024];
    const int tid = threadIdx.x, b = blockIdx.y;
    for (int i = tid; i < 1024; i += 256)
        gg[i] = gelu_exact(G[b * 1024 + i] * (1.0f / (float)SEQ));
    __syncthreads();
    const int w = tid >> 6, lane = tid & 63;
    const int o = blockIdx.x * 4 + w;
    const ushort_t* wr = wctxB + (size_t)o * 1024;
    float acc = 0.f;
    #pragma unroll
    for (int j = 0; j < 16; j++)
        acc += gg[j * 64 + lane] * bf2f(wr[j * 64 + lane]);
    #pragma unroll
    for (int off = 32; off; off >>= 1) acc += __shfl_down(acc, off, 64);
    if (lane == 0) v[b * 1024 + o] = acc;
}

extern "C" void kernel_launch(void* const* d_in, const int* in_sizes, int n_in,
                              void* d_out, int out_size, void* d_ws, size_t ws_size,
                              hipStream_t stream) {
    const float* input = (const float*)d_in[0];
    const float* W_in  = (const float*)d_in[1];
    const float* b_in  = (const float*)d_in[2];
    const float* w0    = (const float*)d_in[3];
    const float* b0    = (const float*)d_in[4];
    const float* w1    = (const float*)d_in[5];
    const float* b1    = (const float*)d_in[6];
    const float* W_ctx = (const float*)d_in[7];
    const float* b_ctx = (const float*)d_in[8];
    const float* W_out = (const float*)d_in[9];
    const float* b_out = (const float*)d_in[10];

    char* ws = (char*)d_ws;
    size_t o = 0;
    ushort_t* ibf   = (ushort_t*)(ws + o); o += (size_t)BS * 1024 * 2;   // input bf16, reused as P
    ushort_t* proj  = (ushort_t*)(ws + o); o += (size_t)BS * 2048 * 2;   // [query | ctx] bf16
    ushort_t* Y     = (ushort_t*)(ws + o); o += (size_t)BS * 1024 * 2;
    float*    gates = (float*)   (ws + o); o += (size_t)BS * 4 * 4;
    float*    G     = (float*)   (ws + o); o += (size_t)BATCH * 1024 * 4;
    float*    v     = (float*)   (ws + o); o += (size_t)BATCH * 1024 * 4;
    float*    wg    = (float*)   (ws + o); o += (size_t)3 * 1024 * 4;
    ushort_t* winT  = (ushort_t*)(ws + o); o += (size_t)2048 * 1024 * 2;
    ushort_t* wctxB = (ushort_t*)(ws + o); o += (size_t)1024 * 1024 * 2;
    ushort_t* woutT = (ushort_t*)(ws + o); o += (size_t)1024 * 1024 * 2;
    ushort_t* P = ibf;   // safe: ibf last read by gemm0; dwconv_fused writes P after

    hipMemsetAsync(G, 0, BATCH * 1024 * sizeof(float), stream);
    // weight prep
    pack_gatesw<<<4, 256, 0, stream>>>(W_in, wg);
    transpose_cvt<<<dim3(2048 / 32, 1024 / 32), 256, 0, stream>>>(W_in, winT, PCOL, 1024);
    cvt_f32_bf16<<<1024 * 1024 / 4 / 256, 256, 0, stream>>>(W_ctx, wctxB, 1024 * 1024);
    transpose_cvt<<<dim3(1024 / 32, 1024 / 32), 256, 0, stream>>>(W_out, woutT, 1024, 1024);
    // input cvt + gates GEMV (fp32)
    cvt_gates<<<BS, 256, 0, stream>>>(input, wg, b_in, ibf, gates);
    // proj[:, 0:2048] = input @ W_in[:, 0:2048] + b_in   (1024 tiles: nbx=8, tpb=4)
    gemm256<0><<<dim3(256), 512, 0, stream>>>(ibf, winT, b_in, proj,
        nullptr, nullptr, nullptr, 1024, 2048, 0, 8, 4);
    // fused conv chain -> P (= c0*g0 + c1*g1), G (= sum_s c1)
    dwconv_fused<<<dim3(SEQ / 64, 16, BATCH), 256, 0, stream>>>(proj, w0, b0, w1, b1, gates, P, G);
    // v[b,:] = gelu(G/SEQ) @ Wctx^T
    gemv_v<<<dim3(256, BATCH), 256, 0, stream>>>(G, wctxB, v);
    // Y = query * (P @ Wctx^T + b_ctx + g2 (x) v)   (512 tiles: nbx=4, tpb=2)
    gemm256<1><<<dim3(256), 512, 0, stream>>>(P, wctxB, b_ctx, Y,
        proj, gates, v, 1024, 1024, 2048, 4, 2);
    // out = Y @ W_out + b_out  (fp32)  (512 tiles: nbx=4, tpb=2)
    gemm256<2><<<dim3(256), 512, 0, stream>>>(Y, woutT, b_out, d_out,
        nullptr, nullptr, nullptr, 1024, 1024, 0, 4, 2);
}

// Round 7
// 662.707 us; speedup vs baseline: 1.0761x; 1.0024x over previous
//
#include <hip/hip_runtime.h>

#define DIMC 1024
#define BATCH 8
#define SEQ 4096
#define BS (BATCH*SEQ)   // 32768
#define PCOL 2051

typedef unsigned short ushort_t;
typedef __attribute__((ext_vector_type(8))) short short8;
typedef __attribute__((ext_vector_type(4))) float f32x4;
typedef __attribute__((ext_vector_type(4))) unsigned short us4;

__device__ __forceinline__ float bf2f(ushort_t u) {
    union { unsigned u32; float f; } v; v.u32 = ((unsigned)u) << 16; return v.f;
}
__device__ __forceinline__ ushort_t f2bf(float f) {
    union { float f; unsigned u; } v; v.f = f;
    unsigned r = v.u + 0x7fffu + ((v.u >> 16) & 1u);
    return (ushort_t)(r >> 16);
}
__device__ __forceinline__ float gelu_exact(float x) {
    return 0.5f * x * (1.0f + erff(x * 0.7071067811865475f));
}
__device__ __forceinline__ void gld16(const ushort_t* g, ushort_t* l) {
    __builtin_amdgcn_global_load_lds(
        (const __attribute__((address_space(1))) unsigned int*)g,
        (__attribute__((address_space(3))) unsigned int*)l, 16, 0, 0);
}

// ---------------- elementwise f32 -> bf16 ----------------
__global__ void cvt_f32_bf16(const float* __restrict__ src, ushort_t* __restrict__ dst, int n) {
    int i = (blockIdx.x * 256 + threadIdx.x) * 4;
    if (i >= n) return;
    f32x4 v = *(const f32x4*)(src + i);
    us4 o;
    #pragma unroll
    for (int j = 0; j < 4; j++) o[j] = f2bf(v[j]);
    *(us4*)(dst + i) = o;
}

// ---------------- transpose + cvt: dst[n*K + k] = src[k*ld + n] ----------------
__global__ void transpose_cvt(const float* __restrict__ src, ushort_t* __restrict__ dst,
                              int ld, int K) {
    __shared__ float tile[32][33];
    int tx = threadIdx.x & 31, ty = threadIdx.x >> 5;   // 32 x 8
    int n0 = blockIdx.x * 32, k0 = blockIdx.y * 32;
    #pragma unroll
    for (int j = 0; j < 4; j++)
        tile[ty + j * 8][tx] = src[(size_t)(k0 + ty + j * 8) * ld + n0 + tx];
    __syncthreads();
    #pragma unroll
    for (int j = 0; j < 4; j++)
        dst[(size_t)(n0 + ty + j * 8) * K + k0 + tx] = f2bf(tile[tx][ty + j * 8]);
}

// ---------------- pack gate weight columns: wg[j*1024+d] = W_in[d*PCOL + 2048+j] ----------------
__global__ void pack_gatesw(const float* __restrict__ W_in, float* __restrict__ wg) {
    int d = blockIdx.x * 256 + threadIdx.x;
    if (d >= 1024) return;
    const float* p = W_in + (size_t)d * PCOL + 2048;
    wg[d] = p[0]; wg[1024 + d] = p[1]; wg[2048 + d] = p[2];
}

// ---------------- fused: ibf = bf16(input); gates[row] = input[row] . wg + b_in ----------------
__global__ void cvt_gates(const float* __restrict__ input, const float* __restrict__ wg,
                          const float* __restrict__ b_in, ushort_t* __restrict__ ibf,
                          float* __restrict__ gates) {
    int row = blockIdx.x, tid = threadIdx.x;
    int lane = tid & 63, wave = tid >> 6;
    size_t base = (size_t)row * 1024 + tid * 4;
    f32x4 v = *(const f32x4*)(input + base);
    us4 o;
    #pragma unroll
    for (int j = 0; j < 4; j++) o[j] = f2bf(v[j]);
    *(us4*)(ibf + base) = o;
    f32x4 w0v = *(const f32x4*)(wg + tid * 4);
    f32x4 w1v = *(const f32x4*)(wg + 1024 + tid * 4);
    f32x4 w2v = *(const f32x4*)(wg + 2048 + tid * 4);
    float a0 = 0, a1 = 0, a2 = 0;
    #pragma unroll
    for (int j = 0; j < 4; j++) { a0 += v[j] * w0v[j]; a1 += v[j] * w1v[j]; a2 += v[j] * w2v[j]; }
    #pragma unroll
    for (int off = 32; off; off >>= 1) {
        a0 += __shfl_down(a0, off, 64);
        a1 += __shfl_down(a1, off, 64);
        a2 += __shfl_down(a2, off, 64);
    }
    __shared__ float red[4][3];
    if (lane == 0) { red[wave][0] = a0; red[wave][1] = a1; red[wave][2] = a2; }
    __syncthreads();
    if (tid == 0) {
        gates[row * 4 + 0] = red[0][0] + red[1][0] + red[2][0] + red[3][0] + b_in[2048];
        gates[row * 4 + 1] = red[0][1] + red[1][1] + red[2][1] + red[3][1] + b_in[2049];
        gates[row * 4 + 2] = red[0][2] + red[1][2] + red[2][2] + red[3][2] + b_in[2050];
    }
}

// ============ 256x256 4-phase (merged) bf16 MFMA GEMM, persistent ============
// Same work/stages/accumulation order as the verified 8-phase schedule, but
// phases merged pairwise: 32 MFMA per phase, HALF the barriers + lgkm drains.
// Merged iter (k-tiles t=2it in buf0, t+1 in buf1):
//  M1: reads lA[0] q0,q1 + lB[0] bfr; stage A(t+1)->lA[1]; 32 MFMA
//  M2: reads lA[0] q2,q3;             stage B(t+2)->lB[0]; 32 MFMA; vmcnt(4)
//  M3: reads lA[1] q0,q1 + lB[1] bfr; stage A(t+2)->lA[0]; 32 MFMA
//  M4: reads lA[1] q2,q3;             stage B(t+3)->lB[1]; 32 MFMA; vmcnt(4)
// Ledger: M2-end 12 in flight -> leave 4 (B(t+2)) drains A(t+1),B(t+1) before
// M3 reads them; M4-end leaves B(t+3), drains A(t+2),B(t+2) before next M1.
// bn-INNER persistent traversal (R4 best): A panel constant per block (hot).
template<int MODE>
__global__ __launch_bounds__(512, 2)
void gemm256(const ushort_t* __restrict__ A, const ushort_t* __restrict__ Bt,
             const float* __restrict__ bias, void* __restrict__ C,
             const ushort_t* __restrict__ Q, const float* __restrict__ gates,
             const float* __restrict__ vb, int K, int ldc, int ldq, int nbx, int tpb) {
    __shared__ ushort_t lA[2][16384];
    __shared__ ushort_t lB[2][16384];
    const int tid = threadIdx.x, lane = tid & 63, wave = tid >> 6;
    const int lr = lane & 15, kq = lane >> 4;
    const int wrm = wave >> 2, wrn = wave & 3;

    // T1: xcd = bid&7 owns a contiguous chunk of the tile space (bn-inner)
    const int bid = blockIdx.x;
    const int chunk = (gridDim.x >> 3) * tpb;
    const int tile0 = (bid & 7) * chunk + (bid >> 3) * tpb;

    // swizzled fragment read base (ushort index): chunk col XOR'd by row-bit-3
    const int xsw = kq ^ (((lr >> 3) & 1) << 1);
    const int fBase = lr * 32 + xsw * 8;

    // staging: per-thread inverse-swizzled global source offsets (ushort units),
    // wave-uniform LDS chunk bases. [h = half (128 rows)][j = load index]
    int srOff[2][2], ldsC[2][2];
    #pragma unroll
    for (int h = 0; h < 2; h++)
        #pragma unroll
        for (int j = 0; j < 2; j++) {
            int c = h * 1024 + j * 512 + tid;           // linear 16B-chunk id in tile
            int sub = c >> 6, rl = (c >> 2) & 15, cc = c & 3;
            int r  = ((sub >> 1) << 4) | rl;
            int k8 = ((sub & 1) << 2) | (cc ^ (((rl >> 3) & 1) << 1));
            srOff[h][j] = r * K + k8 * 8;
            ldsC[h][j]  = (h * 1024 + j * 512 + (wave << 6)) << 3;
        }

    f32x4 acc[8][4];
    short8 af4[2][2][2], bfr[4][2];   // af4[q][mi][k8] for the 2 quadrants of a merged phase

#define STG(ARR, bb, G, kt, h) do { \
    gld16((G) + (size_t)(kt) * 64 + srOff[h][0], &ARR[bb][ldsC[h][0]]); \
    gld16((G) + (size_t)(kt) * 64 + srOff[h][1], &ARR[bb][ldsC[h][1]]); \
} while (0)

// Merged phase: half=0 -> quadrants qq={0,1} (+B-frag loads); half=1 -> qq={2,3}.
#define PHASE2(bb, half, STAGE_STMT, DOVM) do { \
    if ((half) == 0) { \
        _Pragma("unroll") \
        for (int nt = 0; nt < 4; nt++) { \
            bfr[nt][0] = *(const short8*)&lB[bb][fBase + ((wrn * 4 + nt) * 2 + 0) * 512]; \
            bfr[nt][1] = *(const short8*)&lB[bb][fBase + ((wrn * 4 + nt) * 2 + 1) * 512]; \
        } \
    } \
    _Pragma("unroll") \
    for (int q = 0; q < 2; q++) \
        _Pragma("unroll") \
        for (int mi = 0; mi < 2; mi++) { \
            af4[q][mi][0] = *(const short8*)&lA[bb][fBase + ((wrm * 8 + ((half) * 2 + q) * 2 + mi) * 2 + 0) * 512]; \
            af4[q][mi][1] = *(const short8*)&lA[bb][fBase + ((wrm * 8 + ((half) * 2 + q) * 2 + mi) * 2 + 1) * 512]; \
        } \
    STAGE_STMT; \
    if ((half) == 0) asm volatile("s_waitcnt lgkmcnt(8)" ::: "memory"); \
    __builtin_amdgcn_s_barrier(); \
    asm volatile("s_waitcnt lgkmcnt(0)" ::: "memory"); \
    __builtin_amdgcn_s_setprio(1); \
    _Pragma("unroll") \
    for (int q = 0; q < 2; q++) \
        _Pragma("unroll") \
        for (int mi = 0; mi < 2; mi++) \
            _Pragma("unroll") \
            for (int nt = 0; nt < 4; nt++) { \
                acc[((half) * 2 + q) * 2 + mi][nt] = __builtin_amdgcn_mfma_f32_16x16x32_bf16( \
                    af4[q][mi][0], bfr[nt][0], acc[((half) * 2 + q) * 2 + mi][nt], 0, 0, 0); \
                acc[((half) * 2 + q) * 2 + mi][nt] = __builtin_amdgcn_mfma_f32_16x16x32_bf16( \
                    af4[q][mi][1], bfr[nt][1], acc[((half) * 2 + q) * 2 + mi][nt], 0, 0, 0); \
            } \
    __builtin_amdgcn_s_setprio(0); \
    if (DOVM) asm volatile("s_waitcnt vmcnt(4)" ::: "memory"); \
    __builtin_amdgcn_s_barrier(); \
} while (0)

    const int KT = K >> 6;   // k-tiles per output tile (16)
    const int IT = K >> 7;   // merged iterations (8)

    int j = tile0;
    int bn = j % nbx, bm = j / nbx;
    const ushort_t* Ag = A + (size_t)bm * 256 * K;
    const ushort_t* Bg = Bt + (size_t)bn * 256 * K;

    // block prologue (once): tile j k-tile0 A+B -> buf0, k-tile1 B -> buf1
    STG(lA, 0, Ag, 0, 0); STG(lA, 0, Ag, 0, 1);
    STG(lB, 0, Bg, 0, 0); STG(lB, 0, Bg, 0, 1);
    STG(lB, 1, Bg, 1, 0); STG(lB, 1, Bg, 1, 1);
    asm volatile("s_waitcnt vmcnt(4)" ::: "memory");   // tile0 landed; B(1) in flight
    __builtin_amdgcn_s_barrier();

    for (int ti = 0; ti < tpb; ti++) {
        // next tile (clamped to self on the block's last tile -> dead restage)
        const int jn = (ti < tpb - 1) ? j + 1 : j;
        const int bnn = jn % nbx, bmn = jn / nbx;
        const ushort_t* Agn = A + (size_t)bmn * 256 * K;
        const ushort_t* Bgn = Bt + (size_t)bnn * 256 * K;

        #pragma unroll
        for (int i = 0; i < 8; i++)
            #pragma unroll
            for (int jj = 0; jj < 4; jj++)
                #pragma unroll
                for (int r = 0; r < 4; r++) acc[i][jj][r] = 0.f;

        // steady merged iterations
        for (int it = 0; it < IT - 1; it++) {
            const int t1 = 2 * it + 1, t2 = 2 * it + 2, t3 = 2 * it + 3;
            PHASE2(0, 0, STG(lA, 1, Ag, t1, 0); STG(lA, 1, Ag, t1, 1), 0);
            PHASE2(0, 1, STG(lB, 0, Bg, t2, 0); STG(lB, 0, Bg, t2, 1), 1);
            PHASE2(1, 0, STG(lA, 0, Ag, t2, 0); STG(lA, 0, Ag, t2, 1), 0);
            PHASE2(1, 1, STG(lB, 1, Bg, t3, 0); STG(lB, 1, Bg, t3, 1), 1);
        }
        // boundary iteration: spare slots prefetch NEXT tile's prologue state
        PHASE2(0, 0, STG(lA, 1, Ag, KT - 1, 0); STG(lA, 1, Ag, KT - 1, 1), 0);
        PHASE2(0, 1, STG(lB, 0, Bgn, 0, 0); STG(lB, 0, Bgn, 0, 1), 1);
        PHASE2(1, 0, STG(lA, 0, Agn, 0, 0); STG(lA, 0, Agn, 0, 1), 0);
        PHASE2(1, 1, STG(lB, 1, Bgn, 1, 0); STG(lB, 1, Bgn, 1, 1), 1);

        // register-only epilogue: overlaps the in-flight next-tile prologue.
        const int bbatch = (bm * 256) >> 12;   // batch index (uniform, SEQ=4096)
        float biasv[4], vbv[4];
        #pragma unroll
        for (int nt = 0; nt < 4; nt++) {
            int col = bn * 256 + wrn * 64 + nt * 16 + lr;
            biasv[nt] = bias[col];
            if (MODE == 1) vbv[nt] = vb[bbatch * 1024 + col];
        }
        #pragma unroll
        for (int mt = 0; mt < 8; mt++) {
            #pragma unroll
            for (int r = 0; r < 4; r++) {
                int row = bm * 256 + wrm * 128 + mt * 16 + kq * 4 + r;
                size_t rowc = (size_t)row * ldc;
                float g2;
                if (MODE == 1) g2 = gates[row * 4 + 2];
                #pragma unroll
                for (int nt = 0; nt < 4; nt++) {
                    int col = bn * 256 + wrn * 64 + nt * 16 + lr;
                    float v = acc[mt][nt][r] + biasv[nt];
                    if (MODE == 1) {
                        v += g2 * vbv[nt];
                        v *= bf2f(Q[(size_t)row * ldq + col]);
                    }
                    if (MODE == 2) ((float*)C)[rowc + col] = v;
                    else           ((ushort_t*)C)[rowc + col] = f2bf(v);
                }
            }
        }

        j = jn; bm = bmn; bn = bnn; Ag = Agn; Bg = Bgn;
    }
#undef PHASE2
#undef STG
    // Drain ALL in-flight ops (incl. dead-restage global_load_lds) before exit:
    // stray LDS writes landing after s_endpgm can corrupt a successor block.
    asm volatile("s_waitcnt vmcnt(0) lgkmcnt(0)" ::: "memory");
}

// ---------------- fused dwconv14 -> gelu -> dwconv18 -> gelu -> P = c0*g0 + c1*g1 ----------------
__global__ __launch_bounds__(256)
void dwconv_fused(const ushort_t* __restrict__ proj,   // ld=2048, ctx at col offset 1024
                  const float* __restrict__ w0, const float* __restrict__ b0,
                  const float* __restrict__ w1, const float* __restrict__ b1,
                  const float* __restrict__ gates,
                  ushort_t* __restrict__ P, float* __restrict__ G) {
    __shared__ float xc[94 * 64];
    __shared__ float x0[81 * 64];
    __shared__ float gl[2][64];
    __shared__ float rs[256];
    const int tid = threadIdx.x;
    const int s0 = blockIdx.x * 64, d0 = blockIdx.y * 64, b = blockIdx.z;
    for (int c = tid; c < 94 * 8; c += 256) {
        int r = c >> 3, dd = (c & 7) * 8;
        int s = s0 - 14 + r;
        float f[8];
        if (s >= 0 && s < SEQ) {
            short8 u = *(const short8*)&proj[(size_t)(b * SEQ + s) * 2048 + 1024 + d0 + dd];
            #pragma unroll
            for (int j = 0; j < 8; j++) f[j] = bf2f((ushort_t)u[j]);
        } else {
            #pragma unroll
            for (int j = 0; j < 8; j++) f[j] = 0.f;
        }
        f32x4 v0 = {f[0], f[1], f[2], f[3]}, v1 = {f[4], f[5], f[6], f[7]};
        *(f32x4*)&xc[r * 64 + dd] = v0;
        *(f32x4*)&xc[r * 64 + dd + 4] = v1;
    }
    if (tid < 64) gl[0][tid] = gates[(size_t)(b * SEQ + s0 + tid) * 4 + 0];
    else if (tid < 128) gl[1][tid - 64] = gates[(size_t)(b * SEQ + s0 + tid - 64) * 4 + 1];
    const int d = tid & 63, sc = tid >> 6;
    float wr0[14], wr1[18];
    #pragma unroll
    for (int t = 0; t < 14; t++) wr0[t] = w0[(size_t)(d0 + d) * 14 + t];
    float bb0 = b0[d0 + d];
    #pragma unroll
    for (int t = 0; t < 18; t++) wr1[t] = w1[(size_t)(d0 + d) * 18 + t];
    float bb1 = b1[d0 + d];
    __syncthreads();
    {
        float xw[34];
        int r0 = sc * 20;
        #pragma unroll
        for (int r = 0; r < 34; r++) xw[r] = xc[(r0 + r) * 64 + d];
        #pragma unroll
        for (int i = 0; i < 21; i++) {
            int rr = r0 + i;
            int s = s0 - 8 + rr;
            float acc = bb0;
            #pragma unroll
            for (int t = 0; t < 14; t++) acc += wr0[t] * xw[i + t];
            x0[rr * 64 + d] = (s >= 0 && s < SEQ) ? gelu_exact(acc) : 0.f;
        }
    }
    __syncthreads();
    float xw1[33];
    #pragma unroll
    for (int r = 0; r < 33; r++) xw1[r] = x0[(sc * 16 + r) * 64 + d];
    float psum = 0.f;
    #pragma unroll
    for (int i = 0; i < 16; i++) {
        float acc = bb1;
        #pragma unroll
        for (int t = 0; t < 18; t++) acc += wr1[t] * xw1[i + t];
        float c1 = gelu_exact(acc);
        psum += c1;
        float c0v = xw1[i + 8];
        int sl = sc * 16 + i;
        float pv = c0v * gl[0][sl] + c1 * gl[1][sl];
        P[(size_t)(b * SEQ + s0 + sl) * 1024 + d0 + d] = f2bf(pv);
    }
    rs[tid] = psum;
    __syncthreads();
    if (sc == 0)
        atomicAdd(&G[b * 1024 + d0 + d], rs[d] + rs[64 + d] + rs[128 + d] + rs[192 + d]);
}

// ---------------- v[b,o] = sum_c gelu(G[b,c]/SEQ) * Wctx[o,c] ----------------
__global__ __launch_bounds__(256)
void gemv_v(const float* __restrict__ G, const ushort_t* __restrict__ wctxB,
            float* __restrict__ v) {
    __shared__ float gg[1024];
    const int tid = threadIdx.x, b = blockIdx.y;
    for (int i = tid; i < 1024; i += 256)
        gg[i] = gelu_exact(G[b * 1024 + i] * (1.0f / (float)SEQ));
    __syncthreads();
    const int w = tid >> 6, lane = tid & 63;
    const int o = blockIdx.x * 4 + w;
    const ushort_t* wr = wctxB + (size_t)o * 1024;
    float acc = 0.f;
    #pragma unroll
    for (int j = 0; j < 16; j++)
        acc += gg[j * 64 + lane] * bf2f(wr[j * 64 + lane]);
    #pragma unroll
    for (int off = 32; off; off >>= 1) acc += __shfl_down(acc, off, 64);
    if (lane == 0) v[b * 1024 + o] = acc;
}

extern "C" void kernel_launch(void* const* d_in, const int* in_sizes, int n_in,
                              void* d_out, int out_size, void* d_ws, size_t ws_size,
                              hipStream_t stream) {
    const float* input = (const float*)d_in[0];
    const float* W_in  = (const float*)d_in[1];
    const float* b_in  = (const float*)d_in[2];
    const float* w0    = (const float*)d_in[3];
    const float* b0    = (const float*)d_in[4];
    const float* w1    = (const float*)d_in[5];
    const float* b1    = (const float*)d_in[6];
    const float* W_ctx = (const float*)d_in[7];
    const float* b_ctx = (const float*)d_in[8];
    const float* W_out = (const float*)d_in[9];
    const float* b_out = (const float*)d_in[10];

    char* ws = (char*)d_ws;
    size_t o = 0;
    ushort_t* ibf   = (ushort_t*)(ws + o); o += (size_t)BS * 1024 * 2;   // input bf16, reused as P
    ushort_t* proj  = (ushort_t*)(ws + o); o += (size_t)BS * 2048 * 2;   // [query | ctx] bf16
    ushort_t* Y     = (ushort_t*)(ws + o); o += (size_t)BS * 1024 * 2;
    float*    gates = (float*)   (ws + o); o += (size_t)BS * 4 * 4;
    float*    G     = (float*)   (ws + o); o += (size_t)BATCH * 1024 * 4;
    float*    v     = (float*)   (ws + o); o += (size_t)BATCH * 1024 * 4;
    float*    wg    = (float*)   (ws + o); o += (size_t)3 * 1024 * 4;
    ushort_t* winT  = (ushort_t*)(ws + o); o += (size_t)2048 * 1024 * 2;
    ushort_t* wctxB = (ushort_t*)(ws + o); o += (size_t)1024 * 1024 * 2;
    ushort_t* woutT = (ushort_t*)(ws + o); o += (size_t)1024 * 1024 * 2;
    ushort_t* P = ibf;   // safe: ibf last read by gemm0; dwconv_fused writes P after

    hipMemsetAsync(G, 0, BATCH * 1024 * sizeof(float), stream);
    // weight prep
    pack_gatesw<<<4, 256, 0, stream>>>(W_in, wg);
    transpose_cvt<<<dim3(2048 / 32, 1024 / 32), 256, 0, stream>>>(W_in, winT, PCOL, 1024);
    cvt_f32_bf16<<<1024 * 1024 / 4 / 256, 256, 0, stream>>>(W_ctx, wctxB, 1024 * 1024);
    transpose_cvt<<<dim3(1024 / 32, 1024 / 32), 256, 0, stream>>>(W_out, woutT, 1024, 1024);
    // input cvt + gates GEMV (fp32)
    cvt_gates<<<BS, 256, 0, stream>>>(input, wg, b_in, ibf, gates);
    // proj[:, 0:2048] = input @ W_in[:, 0:2048] + b_in   (1024 tiles: nbx=8, tpb=4)
    gemm256<0><<<dim3(256), 512, 0, stream>>>(ibf, winT, b_in, proj,
        nullptr, nullptr, nullptr, 1024, 2048, 0, 8, 4);
    // fused conv chain -> P (= c0*g0 + c1*g1), G (= sum_s c1)
    dwconv_fused<<<dim3(SEQ / 64, 16, BATCH), 256, 0, stream>>>(proj, w0, b0, w1, b1, gates, P, G);
    // v[b,:] = gelu(G/SEQ) @ Wctx^T
    gemv_v<<<dim3(256, BATCH), 256, 0, stream>>>(G, wctxB, v);
    // Y = query * (P @ Wctx^T + b_ctx + g2 (x) v)   (512 tiles: nbx=4, tpb=2)
    gemm256<1><<<dim3(256), 512, 0, stream>>>(P, wctxB, b_ctx, Y,
        proj, gates, v, 1024, 1024, 2048, 4, 2);
    // out = Y @ W_out + b_out  (fp32)  (512 tiles: nbx=4, tpb=2)
    gemm256<2><<<dim3(256), 512, 0, stream>>>(Y, woutT, b_out, d_out,
        nullptr, nullptr, nullptr, 1024, 1024, 0, 4, 2);
}